// Round 18
// baseline (76.734 us; speedup 1.0000x reference)
//
#include <hip/hip_runtime.h>

typedef __bf16 bf16_t;
typedef float  f32x4_t  __attribute__((ext_vector_type(4)));
typedef bf16_t bf16x4_t __attribute__((ext_vector_type(4)));
typedef bf16_t bf16x8_t __attribute__((ext_vector_type(8)));

#define BATCH  4
#define S_LEN  4096
#define DMODEL 1024
#define HDIM   64
#define NQT    (S_LEN / 16)

// Q pre-scale: 1/sqrt(64) * log2(e)  ->  softmax runs in exp2 domain
#define QSCALE 0.180336879f
#define DTHR   11.5415603f

#define PART_STRIDE_F 8704     // floats per partial: m[256] l[256] + O bf16 256x64

__device__ __forceinline__ float ex2(float x) { return __builtin_amdgcn_exp2f(x); }

__device__ __forceinline__ void gl_lds16(const bf16_t* g, bf16_t* l) {
    __builtin_amdgcn_global_load_lds(
        (const __attribute__((address_space(1))) unsigned int*)g,
        (__attribute__((address_space(3))) unsigned int*)l, 16, 0, 0);
}

// ---------------------------------------------------------------------------
// Kernel 0: transpose+cast W -> Wt[192][1024] bf16.
// ---------------------------------------------------------------------------
__global__ __launch_bounds__(256) void wt_kernel(
    const float* __restrict__ Wk, const float* __restrict__ Wq,
    const float* __restrict__ Wv, bf16_t* __restrict__ Wt)
{
    __shared__ bf16_t t[64][65];
    const float* W = (blockIdx.y == 0) ? Wq : (blockIdx.y == 1) ? Wk : Wv;
    const int k0 = blockIdx.x * 64;
    const int a = threadIdx.x & 63, r = threadIdx.x >> 6;
#pragma unroll
    for (int i = 0; i < 16; ++i) {
        const int k = r + i * 4;
        t[k][a] = (bf16_t)W[(long)(k0 + k) * HDIM + a];
    }
    __syncthreads();
#pragma unroll
    for (int i = 0; i < 16; ++i) {
        const int h = r + i * 4;
        Wt[((long)(blockIdx.y * 64 + h)) * DMODEL + k0 + a] = t[a][h];
    }
}

// ---------------------------------------------------------------------------
// Kernel 1: QKV projection via bf16 MFMA.
// R18: T3 double-buffer.  W staged via global_load_lds width-16 (async, no
// VGPR round-trip) into 2x48KB; x (fp32->bf16 cast forces reg path) staged
// issue-early/write-late into 2x16KB.  ONE barrier per chunk (was 2); next
// chunk's loads stay in flight across the full compute phase.
// LDS contents bitwise-identical to R13: pre-swizzled GLOBAL source + linear
// LDS write == old linear source + swizzled write (both-sides-or-neither).
// Readers untouched.  LDS 137 KB -> 1 block/CU (same as R13).
// ---------------------------------------------------------------------------
__global__ __launch_bounds__(512, 2) void qkv_mfma_kernel(
    const float* __restrict__ x, const bf16_t* __restrict__ Wt,
    const float* __restrict__ bk, const float* __restrict__ bq,
    const float* __restrict__ bv,
    bf16_t* __restrict__ Qb, bf16_t* __restrict__ Kb, bf16_t* __restrict__ Vt)
{
    __shared__ bf16_t xl[2][64 * 128];    // 2 x 16 KB
    __shared__ bf16_t wl[2][192 * 128];   // 2 x 48 KB
    __shared__ bf16_t vs[64][72];         // 9.2 KB

    const int tid  = threadIdx.x;
    const int lane = tid & 63;
    const int w    = tid >> 6;
    const int g    = lane >> 4, n = lane & 15;
    const long rowbase = (long)blockIdx.x * 64;

    const int mrow = (w >> 2) * 32;
    const int ncol = (w & 3) * 48;

    // staging geometry: 16B task s -> row = s>>4, seg = s&15; global column
    // pre-swizzled (seg ^ (row&7)), LDS write linear at element s*8.
    const int wave_base = tid & ~63;   // lane-0 task id offset within task set

    f32x4_t acc[2][3];
#pragma unroll
    for (int mt = 0; mt < 2; ++mt)
#pragma unroll
        for (int nt = 0; nt < 3; ++nt) acc[mt][nt] = (f32x4_t){0.f, 0.f, 0.f, 0.f};

    bf16x8_t xv[2];

    // ---- prologue: stage chunk 0 into buffer 0
#pragma unroll
    for (int i = 0; i < 6; ++i) {
        const int s = tid + i * 512;
        const int row = s >> 4, seg = s & 15;
        gl_lds16(Wt + (long)row * DMODEL + ((seg ^ (row & 7)) * 8),
                 &wl[0][(size_t)(wave_base + i * 512) * 8]);
    }
#pragma unroll
    for (int i = 0; i < 2; ++i) {
        const int s = tid + i * 512;
        const int row = s >> 4, seg = s & 15;
        const float* xp = x + (rowbase + row) * DMODEL + ((seg ^ (row & 7)) * 8);
        const float4 xa = *reinterpret_cast<const float4*>(xp);
        const float4 xb = *reinterpret_cast<const float4*>(xp + 4);
        xv[i][0] = (bf16_t)xa.x; xv[i][1] = (bf16_t)xa.y;
        xv[i][2] = (bf16_t)xa.z; xv[i][3] = (bf16_t)xa.w;
        xv[i][4] = (bf16_t)xb.x; xv[i][5] = (bf16_t)xb.y;
        xv[i][6] = (bf16_t)xb.z; xv[i][7] = (bf16_t)xb.w;
    }
#pragma unroll
    for (int i = 0; i < 2; ++i) {
        const int s = tid + i * 512;
        *reinterpret_cast<bf16x8_t*>(&xl[0][(size_t)s * 8]) = xv[i];
    }
    __syncthreads();   // drains gl_lds (vmcnt) + x writes (lgkm)

    for (int kc = 0; kc < 8; ++kc) {
        const int buf = kc & 1;

        // ---- issue next chunk's staging FIRST (hides under compute)
        if (kc < 7) {
            const int k1 = (kc + 1) * 128;
#pragma unroll
            for (int i = 0; i < 6; ++i) {
                const int s = tid + i * 512;
                const int row = s >> 4, seg = s & 15;
                gl_lds16(Wt + (long)row * DMODEL + k1 + ((seg ^ (row & 7)) * 8),
                         &wl[buf ^ 1][(size_t)(wave_base + i * 512) * 8]);
            }
#pragma unroll
            for (int i = 0; i < 2; ++i) {
                const int s = tid + i * 512;
                const int row = s >> 4, seg = s & 15;
                const float* xp = x + (rowbase + row) * DMODEL + k1 + ((seg ^ (row & 7)) * 8);
                const float4 xa = *reinterpret_cast<const float4*>(xp);
                const float4 xb = *reinterpret_cast<const float4*>(xp + 4);
                xv[i][0] = (bf16_t)xa.x; xv[i][1] = (bf16_t)xa.y;
                xv[i][2] = (bf16_t)xa.z; xv[i][3] = (bf16_t)xa.w;
                xv[i][4] = (bf16_t)xb.x; xv[i][5] = (bf16_t)xb.y;
                xv[i][6] = (bf16_t)xb.z; xv[i][7] = (bf16_t)xb.w;
            }
        }

        // ---- compute chunk kc from buf
#pragma unroll
        for (int ks = 0; ks < 4; ++ks) {
            const int sb = ks * 4;
            bf16x8_t afr[2], bfr[3];
#pragma unroll
            for (int mt = 0; mt < 2; ++mt) {
                const int row = mrow + mt * 16 + n;
                afr[mt] = *reinterpret_cast<const bf16x8_t*>(
                    (char*)&xl[buf][0] + row * 256 + (((sb + g) ^ (row & 7)) * 16));
            }
#pragma unroll
            for (int nt = 0; nt < 3; ++nt) {
                const int row = ncol + nt * 16 + n;
                bfr[nt] = *reinterpret_cast<const bf16x8_t*>(
                    (char*)&wl[buf][0] + row * 256 + (((sb + g) ^ (row & 7)) * 16));
            }
#pragma unroll
            for (int mt = 0; mt < 2; ++mt)
#pragma unroll
                for (int nt = 0; nt < 3; ++nt)
                    acc[mt][nt] = __builtin_amdgcn_mfma_f32_16x16x32_bf16(
                        afr[mt], bfr[nt], acc[mt][nt], 0, 0, 0);
        }

        // ---- write next x into the other buffer (write-late: T14 split)
        if (kc < 7) {
#pragma unroll
            for (int i = 0; i < 2; ++i) {
                const int s = tid + i * 512;
                *reinterpret_cast<bf16x8_t*>(&xl[buf ^ 1][(size_t)s * 8]) = xv[i];
            }
        }
        __syncthreads();   // one barrier per chunk
    }

    // ---- epilogue: bias (+QSCALE for Q), Q/K direct, V via bounce
#pragma unroll
    for (int nt = 0; nt < 3; ++nt) {
        const int c = ncol + nt * 16 + n;
        float bias;
        if (c < 64)       bias = bq[c];
        else if (c < 128) bias = bk[c - 64];
        else              bias = bv[c - 128];
#pragma unroll
        for (int mt = 0; mt < 2; ++mt) {
#pragma unroll
            for (int r = 0; r < 4; ++r) {
                const int row = mrow + mt * 16 + 4 * g + r;
                const float val = acc[mt][nt][r] + bias;
                if (c < 64)
                    Qb[(rowbase + row) * HDIM + c] = (bf16_t)(val * QSCALE);
                else if (c < 128)
                    Kb[(rowbase + row) * HDIM + (c - 64)] = (bf16_t)val;
                else
                    vs[c - 128][row] = (bf16_t)val;
            }
        }
    }
    __syncthreads();
    {
        const int h = tid >> 3, sj = (tid & 7) * 8;
        const int bb = (int)(rowbase >> 12);
        const int s0 = (int)(rowbase & (S_LEN - 1));
        const bf16x8_t vv = *reinterpret_cast<const bf16x8_t*>(&vs[h][sj]);
        *reinterpret_cast<bf16x8_t*>(
            Vt + ((long)(bb * 64 + h)) * S_LEN + s0 + sj) = vv;
    }
}

// ---------------------------------------------------------------------------
// Kernel 2a: flash attention, 8-wave 256-q supertile (R13 inner structure).
// R18: exact-512 grid.  ids [0,480) = non-diag chunks (1 per block);
// ids [480,512) = diag PAIR blocks: (b, qt) and (b+2, qt), each ~62% work,
// so 2 blocks/CU with zero third-round straggler.
// ---------------------------------------------------------------------------
__global__ __launch_bounds__(512, 4) void attn_fa(
    const bf16_t* __restrict__ Qb, const bf16_t* __restrict__ Kb,
    const bf16_t* __restrict__ Vt, float* __restrict__ part)
{
    __shared__ bf16_t kl[2][64 * 64];
    __shared__ bf16_t vl[2][64 * 64];
    __shared__ bf16_t pl[8][32 * 64];

    const int tid  = threadIdx.x;
    const int w    = tid >> 6;
    const int lane = tid & 63;
    const int g    = lane >> 4, n = lane & 15;

    const int id = blockIdx.x;
    int b0, qt, c;
    int nit = 1;
    if (id < 480) {
        b0 = id / 120;
        int rr = id - b0 * 120;
        qt = 1;
        while (rr >= qt) { rr -= qt; ++qt; }
        c = rr;
    } else {
        const int d = id - 480;       // 0..31
        b0 = d >> 4;                  // 0..1; second iteration uses b0+2
        qt = d & 15;
        c  = qt;
        nit = 2;
    }
    const bool diag = (c == qt);
    const int q0    = qt * 256;
    const int kbase = c * 256;

    const f32x4_t zero = {0.f, 0.f, 0.f, 0.f};
    char* const pb  = (char*)&pl[w][0];
    const int  pswz = (n & 7) << 4;

    const int srow = lane >> 3, ssub = lane & 7;
    const int krow = w * 8 + srow;
    const int sseg = (ssub ^ (krow & 7)) * 8;
    const int qw0  = q0 + w * 32;

#pragma unroll 1
    for (int it = 0; it < nit; ++it) {
        const int b = b0 + it * 2;
        const int pidx = b * 136 + (qt * (qt + 1)) / 2 + c;
        const long bS = (long)b * S_LEN;
        const long bV = (long)b * 64;

        bf16x8_t bqf[2][2];
#pragma unroll
        for (int qg = 0; qg < 2; ++qg)
#pragma unroll
            for (int hc = 0; hc < 2; ++hc)
                bqf[qg][hc] = *reinterpret_cast<const bf16x8_t*>(
                    &Qb[(bS + qw0 + qg * 16 + n) * HDIM + hc * 32 + g * 8]);

        f32x4_t o[2][4];
#pragma unroll
        for (int qg = 0; qg < 2; ++qg)
#pragma unroll
            for (int nt = 0; nt < 4; ++nt) o[qg][nt] = zero;
        float m_run[2] = {-1e30f, -1e30f};
        float l_par[2] = {0.f, 0.f};

        gl_lds16(&Kb[(bS + kbase + krow) * HDIM + sseg], &kl[0][w * 512]);
        gl_lds16(&Vt[(bV + krow) * S_LEN + kbase + sseg], &vl[0][w * 512]);
        __syncthreads();

#pragma unroll
        for (int t = 0; t < 4; ++t) {
            const int bufi = t & 1;
            const int kt   = kbase + t * 64;

            if (t < 3) {
                gl_lds16(&Kb[(bS + kt + 64 + krow) * HDIM + sseg], &kl[bufi ^ 1][w * 512]);
                gl_lds16(&Vt[(bV + krow) * S_LEN + kt + 64 + sseg], &vl[bufi ^ 1][w * 512]);
            }

            if (!diag || kt <= qw0) {
                f32x4_t s0[4], s1[4];
                __builtin_amdgcn_s_setprio(1);
#pragma unroll
                for (int f = 0; f < 4; ++f) {
                    const int row = 16 * f + n;
                    const bf16x8_t ka0 = *reinterpret_cast<const bf16x8_t*>(
                        (char*)&kl[bufi][0] + row * 128 + ((g ^ (row & 7)) * 16));
                    const bf16x8_t ka1 = *reinterpret_cast<const bf16x8_t*>(
                        (char*)&kl[bufi][0] + row * 128 + (((4 + g) ^ (row & 7)) * 16));
                    s0[f] = __builtin_amdgcn_mfma_f32_16x16x32_bf16(ka0, bqf[0][0], zero, 0, 0, 0);
                    s0[f] = __builtin_amdgcn_mfma_f32_16x16x32_bf16(ka1, bqf[0][1], s0[f], 0, 0, 0);
                    s1[f] = __builtin_amdgcn_mfma_f32_16x16x32_bf16(ka0, bqf[1][0], zero, 0, 0, 0);
                    s1[f] = __builtin_amdgcn_mfma_f32_16x16x32_bf16(ka1, bqf[1][1], s1[f], 0, 0, 0);
                }
                __builtin_amdgcn_s_setprio(0);

                if (diag) {
                    const int qa = qw0 + n, qbq = qw0 + 16 + n;
#pragma unroll
                    for (int f = 0; f < 4; ++f)
#pragma unroll
                        for (int r = 0; r < 4; ++r) {
                            const int key = kt + 16 * f + 4 * g + r;
                            if (key > qa)  s0[f][r] = -1e30f;
                            if (key > qbq) s1[f][r] = -1e30f;
                        }
                }

#pragma unroll
                for (int qg = 0; qg < 2; ++qg) {
                    f32x4_t* s = qg ? s1 : s0;
                    float pm = fmaxf(
                        fmaxf(fmaxf(s[0][0], s[0][1]), fmaxf(s[0][2], s[0][3])),
                        fmaxf(fmaxf(s[1][0], s[1][1]), fmaxf(s[1][2], s[1][3])));
                    pm = fmaxf(pm, fmaxf(
                        fmaxf(fmaxf(s[2][0], s[2][1]), fmaxf(s[2][2], s[2][3])),
                        fmaxf(fmaxf(s[3][0], s[3][1]), fmaxf(s[3][2], s[3][3]))));
                    pm = fmaxf(pm, __shfl_xor(pm, 16));
                    pm = fmaxf(pm, __shfl_xor(pm, 32));

                    if (__any(pm > m_run[qg] + DTHR)) {
                        const float mn = fmaxf(m_run[qg], pm);
                        const float al = ex2(m_run[qg] - mn);
                        m_run[qg] = mn;
                        l_par[qg] *= al;
#pragma unroll
                        for (int r = 0; r < 4; ++r) {
                            const float ar = __shfl(al, 4 * g + r);
#pragma unroll
                            for (int nt = 0; nt < 4; ++nt) o[qg][nt][r] *= ar;
                        }
                    }

                    const int prow = qg * 16 + n;
#pragma unroll
                    for (int f = 0; f < 4; ++f) {
                        bf16x4_t pk;
#pragma unroll
                        for (int r = 0; r < 4; ++r) {
                            const float p = ex2(s[f][r] - m_run[qg]);
                            l_par[qg] += p;
                            pk[r] = (bf16_t)p;
                        }
                        *reinterpret_cast<bf16x4_t*>(
                            pb + prow * 128 + ((32 * f + 8 * g) ^ pswz)) = pk;
                    }
                }

                __builtin_amdgcn_s_setprio(1);
#pragma unroll
                for (int ks = 0; ks < 2; ++ks) {
                    const bf16x8_t pa0 = *reinterpret_cast<const bf16x8_t*>(
                        pb + n * 128 + ((64 * ks + 16 * g) ^ pswz));
                    const bf16x8_t pa1 = *reinterpret_cast<const bf16x8_t*>(
                        pb + (16 + n) * 128 + ((64 * ks + 16 * g) ^ pswz));
#pragma unroll
                    for (int nt = 0; nt < 4; ++nt) {
                        const int row = 16 * nt + n;
                        const bf16x8_t vbf = *reinterpret_cast<const bf16x8_t*>(
                            (char*)&vl[bufi][0] + row * 128 +
                            (((ks * 4 + g) ^ (row & 7)) * 16));
                        o[0][nt] = __builtin_amdgcn_mfma_f32_16x16x32_bf16(
                            pa0, vbf, o[0][nt], 0, 0, 0);
                        o[1][nt] = __builtin_amdgcn_mfma_f32_16x16x32_bf16(
                            pa1, vbf, o[1][nt], 0, 0, 0);
                    }
                }
                __builtin_amdgcn_s_setprio(0);
            }

            __syncthreads();
        }

        float* pp = part + (size_t)pidx * PART_STRIDE_F;
        bf16_t* po = (bf16_t*)(pp + 512);
#pragma unroll
        for (int qg = 0; qg < 2; ++qg) {
            float ls = l_par[qg];
            ls += __shfl_xor(ls, 16);
            ls += __shfl_xor(ls, 32);
            const int ql = w * 32 + qg * 16;
            if (g == 0) { pp[ql + n] = m_run[qg]; pp[256 + ql + n] = ls; }
#pragma unroll
            for (int nt = 0; nt < 4; ++nt)
#pragma unroll
                for (int r = 0; r < 4; ++r)
                    po[(size_t)(ql + 4 * g + r) * 64 + 16 * nt + n] = (bf16_t)o[qg][nt][r];
        }
    }
}

// ---------------------------------------------------------------------------
// Kernel 2b: merge split-K partials (R17 form: 512 blocks, half-pair decode).
// ---------------------------------------------------------------------------
__global__ __launch_bounds__(512) void attn_merge(
    const float* __restrict__ part, float* __restrict__ out)
{
    __shared__ float als[32][18];
    __shared__ float dinv[32];

    const int id   = blockIdx.x;
    const int qs   = id & 7;
    const int pr   = (id >> 3) & 7;
    const int b    = (id >> 6) & 3;
    const int half = (id >> 8) & 1;
    const int qt   = half ? (15 - pr) : pr;

    const int t   = threadIdx.x;
    const int row = t >> 4;
    const int h0  = (t & 15) * 4;

    const float* base0 = part + (size_t)(b * 136 + qt * (qt + 1) / 2) * PART_STRIDE_F;
    const int nc = qt + 1;

    if (t < 32) {
        const int rr = qs * 32 + t;
        float mm = -1e30f;
        for (int cc = 0; cc < nc; ++cc)
            mm = fmaxf(mm, base0[(size_t)cc * PART_STRIDE_F + rr]);
        float den = 0.f;
        for (int cc = 0; cc < nc; ++cc) {
            const float* pc = base0 + (size_t)cc * PART_STRIDE_F;
            const float a = ex2(pc[rr] - mm);
            als[t][cc] = a;
            den += pc[256 + rr] * a;
        }
        dinv[t] = 1.f / den;
    }
    __syncthreads();

    const int ql = qs * 32 + row;
    float num[4];
#pragma unroll
    for (int i = 0; i < 4; ++i) num[i] = 0.f;
    for (int cc = 0; cc < nc; ++cc) {
        const float a = als[row][cc];
        const bf16x4_t ov = *reinterpret_cast<const bf16x4_t*>(
            (const bf16_t*)(base0 + (size_t)cc * PART_STRIDE_F + 512) +
            (size_t)ql * 64 + h0);
#pragma unroll
        for (int i = 0; i < 4; ++i) num[i] += a * (float)ov[i];
    }
    const float inv = dinv[row];
    float* op = out + ((size_t)b * S_LEN + qt * 256 + ql) * 64 + h0;
#pragma unroll
    for (int i = 0; i < 4; ++i) num[i] *= inv;
    *reinterpret_cast<float4*>(op) = *reinterpret_cast<float4*>(num);
}

// ---------------------------------------------------------------------------
// Kernel 2-fallback (used only if ws too small for partials).
// ---------------------------------------------------------------------------
__global__ __launch_bounds__(512)
void attn_fallback(
    const bf16_t* __restrict__ Qb, const bf16_t* __restrict__ Kb,
    const bf16_t* __restrict__ Vt, float* __restrict__ out)
{
    __shared__ bf16_t plds[8][16 * 64];
    __shared__ float  olds[8][16][64];
    __shared__ float  mlds[8][16];
    __shared__ float  llds[8][16];

    const int tid  = threadIdx.x;
    const int w    = tid >> 6;
    const int lane = tid & 63;
    const int g    = lane >> 4, n = lane & 15;
    const int id = blockIdx.x;
    const int b  = (id & 7) >> 1;
    const int p  = ((id & 1) << 6) + (id >> 3);
    const long bS  = (long)b * S_LEN;
    const long bV  = (long)b * 64;
    const int  swz = (n & 7) << 4;
    const f32x4_t zero = {0.f, 0.f, 0.f, 0.f};
    char* const pb = (char*)plds[w];

#pragma unroll 1
    for (int half = 0; half < 2; ++half) {
        const int tile = half ? (NQT - 1 - p) : p;
        const int q0   = tile * 16;
        const int nkb  = (q0 >> 6) + 1;

        const bf16_t* qbase = &Qb[(bS + q0 + n) * HDIM + g * 8];
        const bf16x8_t bq0 = *reinterpret_cast<const bf16x8_t*>(qbase);
        const bf16x8_t bq1 = *reinterpret_cast<const bf16x8_t*>(qbase + 32);

        f32x4_t o[4];
#pragma unroll
        for (int nt = 0; nt < 4; ++nt) o[nt] = zero;
        float m_run = -1e30f, l_par = 0.f;

#pragma unroll 1
        for (int j = w; j < nkb; j += 8) {
            const int k0 = j * 64;
            const bf16_t* kb = &Kb[(bS + k0 + n) * HDIM + g * 8];
            bf16x8_t kr[8];
#pragma unroll
            for (int f = 0; f < 4; ++f) {
                kr[2 * f]     = *reinterpret_cast<const bf16x8_t*>(kb + f * 16 * HDIM);
                kr[2 * f + 1] = *reinterpret_cast<const bf16x8_t*>(kb + f * 16 * HDIM + 32);
            }
            const bf16_t* vbp = &Vt[(bV + n) * S_LEN + k0 + g * 8];
            bf16x8_t vr[8];
#pragma unroll
            for (int ks = 0; ks < 2; ++ks)
#pragma unroll
                for (int nt = 0; nt < 4; ++nt)
                    vr[ks * 4 + nt] = *reinterpret_cast<const bf16x8_t*>(
                        vbp + (long)(nt * 16) * S_LEN + ks * 32);

            f32x4_t s[4];
#pragma unroll
            for (int f = 0; f < 4; ++f) {
                s[f] = __builtin_amdgcn_mfma_f32_16x16x32_bf16(kr[2 * f],     bq0, zero, 0, 0, 0);
                s[f] = __builtin_amdgcn_mfma_f32_16x16x32_bf16(kr[2 * f + 1], bq1, s[f], 0, 0, 0);
            }
            if (j == nkb - 1) {
                const int q = q0 + n;
#pragma unroll
                for (int f = 0; f < 4; ++f)
#pragma unroll
                    for (int r = 0; r < 4; ++r)
                        if (k0 + 16 * f + 4 * g + r > q) s[f][r] = -1e30f;
            }
            float pm = fmaxf(fmaxf(fmaxf(s[0][0], s[0][1]), fmaxf(s[0][2], s[0][3])),
                             fmaxf(fmaxf(s[1][0], s[1][1]), fmaxf(s[1][2], s[1][3])));
            pm = fmaxf(pm, fmaxf(fmaxf(fmaxf(s[2][0], s[2][1]), fmaxf(s[2][2], s[2][3])),
                                 fmaxf(fmaxf(s[3][0], s[3][1]), fmaxf(s[3][2], s[3][3]))));
            pm = fmaxf(pm, __shfl_xor(pm, 16));
            pm = fmaxf(pm, __shfl_xor(pm, 32));
            if (__any(pm > m_run + DTHR)) {
                const float mn = fmaxf(m_run, pm);
                const float al = ex2(m_run - mn);
                m_run = mn; l_par *= al;
#pragma unroll
                for (int r = 0; r < 4; ++r) {
                    const float ar = __shfl(al, 4 * g + r);
#pragma unroll
                    for (int nt = 0; nt < 4; ++nt) o[nt][r] *= ar;
                }
            }
#pragma unroll
            for (int f = 0; f < 4; ++f) {
                bf16x4_t pk;
#pragma unroll
                for (int r = 0; r < 4; ++r) {
                    const float p2 = ex2(s[f][r] - m_run);
                    l_par += p2;
                    pk[r] = (bf16_t)p2;
                }
                *reinterpret_cast<bf16x4_t*>(pb + n * 128 + ((32 * f + 8 * g) ^ swz)) = pk;
            }
#pragma unroll
            for (int ks = 0; ks < 2; ++ks) {
                const bf16x8_t pa = *reinterpret_cast<const bf16x8_t*>(
                    pb + n * 128 + ((64 * ks + 16 * g) ^ swz));
#pragma unroll
                for (int nt = 0; nt < 4; ++nt)
                    o[nt] = __builtin_amdgcn_mfma_f32_16x16x32_bf16(
                        pa, vr[ks * 4 + nt], o[nt], 0, 0, 0);
            }
        }

        float l_run = l_par;
        l_run += __shfl_xor(l_run, 16);
        l_run += __shfl_xor(l_run, 32);
        if (g == 0) { mlds[w][n] = m_run; llds[w][n] = l_run; }
#pragma unroll
        for (int nt = 0; nt < 4; ++nt)
#pragma unroll
            for (int r = 0; r < 4; ++r)
                olds[w][4 * g + r][nt * 16 + n] = o[nt][r];
        __syncthreads();
        {
            const int cc = tid & 63;
            const int rg = tid >> 6;
#pragma unroll
            for (int i = 0; i < 2; ++i) {
                const int row = rg * 2 + i;
                float mmx = mlds[0][row];
#pragma unroll
                for (int u = 1; u < 8; ++u) mmx = fmaxf(mmx, mlds[u][row]);
                float den = 0.f, num = 0.f;
#pragma unroll
                for (int u = 0; u < 8; ++u) {
                    const float a = ex2(mlds[u][row] - mmx);
                    den += llds[u][row] * a;
                    num += olds[u][row][cc] * a;
                }
                out[(bS + q0 + row) * HDIM + cc] = num / den;
            }
        }
        __syncthreads();
    }
}

// ---------------------------------------------------------------------------
extern "C" void kernel_launch(void* const* d_in, const int* in_sizes, int n_in,
                              void* d_out, int out_size, void* d_ws, size_t ws_size,
                              hipStream_t stream)
{
    const float* x  = (const float*)d_in[0];
    const float* Wk = (const float*)d_in[1];
    const float* bk = (const float*)d_in[2];
    const float* Wq = (const float*)d_in[3];
    const float* bq = (const float*)d_in[4];
    const float* Wv = (const float*)d_in[5];
    const float* bv = (const float*)d_in[6];
    float* out = (float*)d_out;

    const size_t elems = (size_t)BATCH * S_LEN * HDIM;  // 1,048,576
    bf16_t* Qb = (bf16_t*)d_ws;
    bf16_t* Kb = Qb + elems;
    bf16_t* Vt = Kb + elems;
    bf16_t* Wt = Vt + elems;                 // 192*1024 bf16
    float*  part = (float*)((char*)d_ws + 6684672);   // 256-aligned

    const size_t needed = 6684672ull + 544ull * (size_t)PART_STRIDE_F * 4ull;

    wt_kernel<<<dim3(DMODEL / 64, 3), 256, 0, stream>>>(Wk, Wq, Wv, Wt);
    qkv_mfma_kernel<<<256, 512, 0, stream>>>(x, Wt, bk, bq, bv, Qb, Kb, Vt);
    if (ws_size >= needed) {
        attn_fa<<<512, 512, 0, stream>>>(Qb, Kb, Vt, part);
        attn_merge<<<512, 512, 0, stream>>>(part, out);
    } else {
        attn_fallback<<<512, 512, 0, stream>>>(Qb, Kb, Vt, out);
    }
}

// Round 19
// 62.118 us; speedup vs baseline: 1.2353x; 1.2353x over previous
//
#include <hip/hip_runtime.h>

typedef __bf16 bf16_t;
typedef float  f32x4_t  __attribute__((ext_vector_type(4)));
typedef bf16_t bf16x4_t __attribute__((ext_vector_type(4)));
typedef bf16_t bf16x8_t __attribute__((ext_vector_type(8)));

#define BATCH  4
#define S_LEN  4096
#define DMODEL 1024
#define HDIM   64
#define NQT    (S_LEN / 16)    // 16-row q-tiles per batch (fallback path)

// Q pre-scale: 1/sqrt(64) * log2(e)  ->  softmax runs in exp2 domain
#define QSCALE 0.180336879f
#define DTHR   11.5415603f

#define PART_STRIDE_F 8704     // floats per partial: m[256] l[256] + O bf16 256x64

__device__ __forceinline__ float ex2(float x) { return __builtin_amdgcn_exp2f(x); }

__device__ __forceinline__ void gl_lds16(const bf16_t* g, bf16_t* l) {
    __builtin_amdgcn_global_load_lds(
        (const __attribute__((address_space(1))) unsigned int*)g,
        (__attribute__((address_space(3))) unsigned int*)l, 16, 0, 0);
}

// ---------------------------------------------------------------------------
// Kernel 0: transpose+cast W -> Wt[192][1024] bf16.
// ---------------------------------------------------------------------------
__global__ __launch_bounds__(256) void wt_kernel(
    const float* __restrict__ Wk, const float* __restrict__ Wq,
    const float* __restrict__ Wv, bf16_t* __restrict__ Wt)
{
    __shared__ bf16_t t[64][65];
    const float* W = (blockIdx.y == 0) ? Wq : (blockIdx.y == 1) ? Wk : Wv;
    const int k0 = blockIdx.x * 64;
    const int a = threadIdx.x & 63, r = threadIdx.x >> 6;
#pragma unroll
    for (int i = 0; i < 16; ++i) {
        const int k = r + i * 4;
        t[k][a] = (bf16_t)W[(long)(k0 + k) * HDIM + a];
    }
    __syncthreads();
#pragma unroll
    for (int i = 0; i < 16; ++i) {
        const int h = r + i * 4;
        Wt[((long)(blockIdx.y * 64 + h)) * DMODEL + k0 + a] = t[a][h];
    }
}

// ---------------------------------------------------------------------------
// Kernel 1: QKV projection via bf16 MFMA (fp32 accum).  R13 form (proven) --
// R18's gl_lds double-buffer rewrite was neutral-to-negative; reverted.
// ---------------------------------------------------------------------------
__global__ __launch_bounds__(512, 2) void qkv_mfma_kernel(
    const float* __restrict__ x, const bf16_t* __restrict__ Wt,
    const float* __restrict__ bk, const float* __restrict__ bq,
    const float* __restrict__ bv,
    bf16_t* __restrict__ Qb, bf16_t* __restrict__ Kb, bf16_t* __restrict__ Vt)
{
    __shared__ bf16_t xs[64 * 128];   // 16 KB, swizzled, 256B row stride
    __shared__ bf16_t ws[192 * 128];  // 48 KB, swizzled
    __shared__ bf16_t vs[64][72];     // V bounce, 9.2 KB

    const int tid  = threadIdx.x;
    const int lane = tid & 63;
    const int w    = tid >> 6;
    const int g    = lane >> 4, n = lane & 15;
    const long rowbase = (long)blockIdx.x * 64;

    const int mrow = (w >> 2) * 32;
    const int ncol = (w & 3) * 48;

    f32x4_t acc[2][3];
#pragma unroll
    for (int mt = 0; mt < 2; ++mt)
#pragma unroll
        for (int nt = 0; nt < 3; ++nt) acc[mt][nt] = (f32x4_t){0.f, 0.f, 0.f, 0.f};

    for (int kc = 0; kc < 8; ++kc) {
        const int k0 = kc * 128;
        bf16x8_t xv[2];
#pragma unroll
        for (int i = 0; i < 2; ++i) {
            const int s = tid + i * 512;
            const int xrow = s >> 4, xseg = s & 15;
            const float* xp = x + (rowbase + xrow) * DMODEL + k0 + xseg * 8;
            const float4 xa = *reinterpret_cast<const float4*>(xp);
            const float4 xb = *reinterpret_cast<const float4*>(xp + 4);
            xv[i][0] = (bf16_t)xa.x; xv[i][1] = (bf16_t)xa.y;
            xv[i][2] = (bf16_t)xa.z; xv[i][3] = (bf16_t)xa.w;
            xv[i][4] = (bf16_t)xb.x; xv[i][5] = (bf16_t)xb.y;
            xv[i][6] = (bf16_t)xb.z; xv[i][7] = (bf16_t)xb.w;
        }
        bf16x8_t wreg[6];
#pragma unroll
        for (int i = 0; i < 6; ++i) {
            const int s = tid + i * 512;
            wreg[i] = *reinterpret_cast<const bf16x8_t*>(
                Wt + ((long)(s >> 4)) * DMODEL + k0 + (s & 15) * 8);
        }

        __syncthreads();
#pragma unroll
        for (int i = 0; i < 2; ++i) {
            const int s = tid + i * 512;
            const int row = s >> 4, seg = s & 15;
            *reinterpret_cast<bf16x8_t*>(
                (char*)xs + row * 256 + ((seg ^ (row & 7)) * 16)) = xv[i];
        }
#pragma unroll
        for (int i = 0; i < 6; ++i) {
            const int s = tid + i * 512;
            const int row = s >> 4, seg = s & 15;
            *reinterpret_cast<bf16x8_t*>(
                (char*)ws + row * 256 + ((seg ^ (row & 7)) * 16)) = wreg[i];
        }
        __syncthreads();

#pragma unroll
        for (int ks = 0; ks < 4; ++ks) {
            const int sb = ks * 4;
            bf16x8_t afr[2], bfr[3];
#pragma unroll
            for (int mt = 0; mt < 2; ++mt) {
                const int row = mrow + mt * 16 + n;
                afr[mt] = *reinterpret_cast<const bf16x8_t*>(
                    (char*)xs + row * 256 + (((sb + g) ^ (row & 7)) * 16));
            }
#pragma unroll
            for (int nt = 0; nt < 3; ++nt) {
                const int row = ncol + nt * 16 + n;
                bfr[nt] = *reinterpret_cast<const bf16x8_t*>(
                    (char*)ws + row * 256 + (((sb + g) ^ (row & 7)) * 16));
            }
#pragma unroll
            for (int mt = 0; mt < 2; ++mt)
#pragma unroll
                for (int nt = 0; nt < 3; ++nt)
                    acc[mt][nt] = __builtin_amdgcn_mfma_f32_16x16x32_bf16(
                        afr[mt], bfr[nt], acc[mt][nt], 0, 0, 0);
        }
    }

#pragma unroll
    for (int nt = 0; nt < 3; ++nt) {
        const int c = ncol + nt * 16 + n;
        float bias;
        if (c < 64)       bias = bq[c];
        else if (c < 128) bias = bk[c - 64];
        else              bias = bv[c - 128];
#pragma unroll
        for (int mt = 0; mt < 2; ++mt) {
#pragma unroll
            for (int r = 0; r < 4; ++r) {
                const int row = mrow + mt * 16 + 4 * g + r;
                const float val = acc[mt][nt][r] + bias;
                if (c < 64)
                    Qb[(rowbase + row) * HDIM + c] = (bf16_t)(val * QSCALE);
                else if (c < 128)
                    Kb[(rowbase + row) * HDIM + (c - 64)] = (bf16_t)val;
                else
                    vs[c - 128][row] = (bf16_t)val;
            }
        }
    }
    __syncthreads();
    {
        const int h = tid >> 3, sj = (tid & 7) * 8;
        const int bb = (int)(rowbase >> 12);
        const int s0 = (int)(rowbase & (S_LEN - 1));
        const bf16x8_t vv = *reinterpret_cast<const bf16x8_t*>(&vs[h][sj]);
        *reinterpret_cast<bf16x8_t*>(
            Vt + ((long)(bb * 64 + h)) * S_LEN + s0 + sj) = vv;
    }
}

// ---------------------------------------------------------------------------
// Kernel 2a: flash attention, 8-wave 256-q supertile.  R13/R17 form (proven).
// 544 blocks; diag chunks last (backfill-balanced tail).  R18's 512-block
// pair scheme regressed (diag chunks are FULL wall-cost: barrier-synced
// critical path = wave 7's 4 tiles), reverted.
// ---------------------------------------------------------------------------
__global__ __launch_bounds__(512, 4) void attn_fa(
    const bf16_t* __restrict__ Qb, const bf16_t* __restrict__ Kb,
    const bf16_t* __restrict__ Vt, float* __restrict__ part)
{
    __shared__ bf16_t kl[2][64 * 64];
    __shared__ bf16_t vl[2][64 * 64];
    __shared__ bf16_t pl[8][32 * 64];

    const int tid  = threadIdx.x;
    const int w    = tid >> 6;
    const int lane = tid & 63;
    const int g    = lane >> 4, n = lane & 15;

    // decode: ids [0,480) = non-diag chunks, [480,544) = diag chunks (last)
    const int id = blockIdx.x;
    int b, qt, c;
    if (id < 480) {
        b = id / 120;
        int rr = id - b * 120;
        qt = 1;
        while (rr >= qt) { rr -= qt; ++qt; }
        c = rr;
    } else {
        const int d = id - 480;
        b = d >> 4;
        qt = d & 15;
        c = qt;
    }
    const bool diag = (c == qt);
    const int q0    = qt * 256;
    const int kbase = c * 256;
    const int pidx  = b * 136 + (qt * (qt + 1)) / 2 + c;

    const long bS = (long)b * S_LEN;
    const long bV = (long)b * 64;
    const int qw0 = q0 + w * 32;

    bf16x8_t bqf[2][2];
#pragma unroll
    for (int qg = 0; qg < 2; ++qg)
#pragma unroll
        for (int hc = 0; hc < 2; ++hc)
            bqf[qg][hc] = *reinterpret_cast<const bf16x8_t*>(
                &Qb[(bS + qw0 + qg * 16 + n) * HDIM + hc * 32 + g * 8]);

    f32x4_t o[2][4];
#pragma unroll
    for (int qg = 0; qg < 2; ++qg)
#pragma unroll
        for (int nt = 0; nt < 4; ++nt) o[qg][nt] = (f32x4_t){0.f, 0.f, 0.f, 0.f};
    float m_run[2] = {-1e30f, -1e30f};
    float l_par[2] = {0.f, 0.f};

    const f32x4_t zero = {0.f, 0.f, 0.f, 0.f};
    char* const pb  = (char*)&pl[w][0];
    const int  pswz = (n & 7) << 4;

    const int srow = lane >> 3, ssub = lane & 7;
    const int krow = w * 8 + srow;
    const int sseg = (ssub ^ (krow & 7)) * 8;

    gl_lds16(&Kb[(bS + kbase + krow) * HDIM + sseg], &kl[0][w * 512]);
    gl_lds16(&Vt[(bV + krow) * S_LEN + kbase + sseg], &vl[0][w * 512]);
    __syncthreads();

#pragma unroll
    for (int t = 0; t < 4; ++t) {
        const int bufi = t & 1;
        const int kt   = kbase + t * 64;

        if (t < 3) {
            gl_lds16(&Kb[(bS + kt + 64 + krow) * HDIM + sseg], &kl[bufi ^ 1][w * 512]);
            gl_lds16(&Vt[(bV + krow) * S_LEN + kt + 64 + sseg], &vl[bufi ^ 1][w * 512]);
        }

        if (!diag || kt <= qw0) {
            f32x4_t s0[4], s1[4];
            __builtin_amdgcn_s_setprio(1);
#pragma unroll
            for (int f = 0; f < 4; ++f) {
                const int row = 16 * f + n;
                const bf16x8_t ka0 = *reinterpret_cast<const bf16x8_t*>(
                    (char*)&kl[bufi][0] + row * 128 + ((g ^ (row & 7)) * 16));
                const bf16x8_t ka1 = *reinterpret_cast<const bf16x8_t*>(
                    (char*)&kl[bufi][0] + row * 128 + (((4 + g) ^ (row & 7)) * 16));
                s0[f] = __builtin_amdgcn_mfma_f32_16x16x32_bf16(ka0, bqf[0][0], zero, 0, 0, 0);
                s0[f] = __builtin_amdgcn_mfma_f32_16x16x32_bf16(ka1, bqf[0][1], s0[f], 0, 0, 0);
                s1[f] = __builtin_amdgcn_mfma_f32_16x16x32_bf16(ka0, bqf[1][0], zero, 0, 0, 0);
                s1[f] = __builtin_amdgcn_mfma_f32_16x16x32_bf16(ka1, bqf[1][1], s1[f], 0, 0, 0);
            }
            __builtin_amdgcn_s_setprio(0);

            if (diag) {
                const int qa = qw0 + n, qbq = qw0 + 16 + n;
#pragma unroll
                for (int f = 0; f < 4; ++f)
#pragma unroll
                    for (int r = 0; r < 4; ++r) {
                        const int key = kt + 16 * f + 4 * g + r;
                        if (key > qa)  s0[f][r] = -1e30f;
                        if (key > qbq) s1[f][r] = -1e30f;
                    }
            }

#pragma unroll
            for (int qg = 0; qg < 2; ++qg) {
                f32x4_t* s = qg ? s1 : s0;
                float pm = fmaxf(
                    fmaxf(fmaxf(s[0][0], s[0][1]), fmaxf(s[0][2], s[0][3])),
                    fmaxf(fmaxf(s[1][0], s[1][1]), fmaxf(s[1][2], s[1][3])));
                pm = fmaxf(pm, fmaxf(
                    fmaxf(fmaxf(s[2][0], s[2][1]), fmaxf(s[2][2], s[2][3])),
                    fmaxf(fmaxf(s[3][0], s[3][1]), fmaxf(s[3][2], s[3][3]))));
                pm = fmaxf(pm, __shfl_xor(pm, 16));
                pm = fmaxf(pm, __shfl_xor(pm, 32));

                if (__any(pm > m_run[qg] + DTHR)) {
                    const float mn = fmaxf(m_run[qg], pm);
                    const float al = ex2(m_run[qg] - mn);
                    m_run[qg] = mn;
                    l_par[qg] *= al;
#pragma unroll
                    for (int r = 0; r < 4; ++r) {
                        const float ar = __shfl(al, 4 * g + r);
#pragma unroll
                        for (int nt = 0; nt < 4; ++nt) o[qg][nt][r] *= ar;
                    }
                }

                const int prow = qg * 16 + n;
#pragma unroll
                for (int f = 0; f < 4; ++f) {
                    bf16x4_t pk;
#pragma unroll
                    for (int r = 0; r < 4; ++r) {
                        const float p = ex2(s[f][r] - m_run[qg]);
                        l_par[qg] += p;
                        pk[r] = (bf16_t)p;
                    }
                    *reinterpret_cast<bf16x4_t*>(
                        pb + prow * 128 + ((32 * f + 8 * g) ^ pswz)) = pk;
                }
            }

            __builtin_amdgcn_s_setprio(1);
#pragma unroll
            for (int ks = 0; ks < 2; ++ks) {
                const bf16x8_t pa0 = *reinterpret_cast<const bf16x8_t*>(
                    pb + n * 128 + ((64 * ks + 16 * g) ^ pswz));
                const bf16x8_t pa1 = *reinterpret_cast<const bf16x8_t*>(
                    pb + (16 + n) * 128 + ((64 * ks + 16 * g) ^ pswz));
#pragma unroll
                for (int nt = 0; nt < 4; ++nt) {
                    const int row = 16 * nt + n;
                    const bf16x8_t vbf = *reinterpret_cast<const bf16x8_t*>(
                        (char*)&vl[bufi][0] + row * 128 +
                        (((ks * 4 + g) ^ (row & 7)) * 16));
                    o[0][nt] = __builtin_amdgcn_mfma_f32_16x16x32_bf16(
                        pa0, vbf, o[0][nt], 0, 0, 0);
                    o[1][nt] = __builtin_amdgcn_mfma_f32_16x16x32_bf16(
                        pa1, vbf, o[1][nt], 0, 0, 0);
                }
            }
            __builtin_amdgcn_s_setprio(0);
        }

        __syncthreads();
    }

    float* pp = part + (size_t)pidx * PART_STRIDE_F;
    bf16_t* po = (bf16_t*)(pp + 512);
#pragma unroll
    for (int qg = 0; qg < 2; ++qg) {
        float ls = l_par[qg];
        ls += __shfl_xor(ls, 16);
        ls += __shfl_xor(ls, 32);
        const int ql = w * 32 + qg * 16;
        if (g == 0) { pp[ql + n] = m_run[qg]; pp[256 + ql + n] = ls; }
#pragma unroll
        for (int nt = 0; nt < 4; ++nt)
#pragma unroll
            for (int r = 0; r < 4; ++r)
                po[(size_t)(ql + 4 * g + r) * 64 + 16 * nt + n] = (bf16_t)o[qg][nt][r];
    }
}

// ---------------------------------------------------------------------------
// Kernel 2b: merge split-K partials (R17 form: 512 blocks, half-pair decode).
// ---------------------------------------------------------------------------
__global__ __launch_bounds__(512) void attn_merge(
    const float* __restrict__ part, float* __restrict__ out)
{
    __shared__ float als[32][18];
    __shared__ float dinv[32];

    const int id   = blockIdx.x;            // 512 blocks
    const int qs   = id & 7;
    const int pr   = (id >> 3) & 7;
    const int b    = (id >> 6) & 3;
    const int half = (id >> 8) & 1;
    const int qt   = half ? (15 - pr) : pr;

    const int t   = threadIdx.x;
    const int row = t >> 4;          // 0..31
    const int h0  = (t & 15) * 4;    // 0..60

    const float* base0 = part + (size_t)(b * 136 + qt * (qt + 1) / 2) * PART_STRIDE_F;
    const int nc = qt + 1;

    if (t < 32) {
        const int rr = qs * 32 + t;
        float mm = -1e30f;
        for (int cc = 0; cc < nc; ++cc)
            mm = fmaxf(mm, base0[(size_t)cc * PART_STRIDE_F + rr]);
        float den = 0.f;
        for (int cc = 0; cc < nc; ++cc) {
            const float* pc = base0 + (size_t)cc * PART_STRIDE_F;
            const float a = ex2(pc[rr] - mm);
            als[t][cc] = a;
            den += pc[256 + rr] * a;
        }
        dinv[t] = 1.f / den;
    }
    __syncthreads();

    const int ql = qs * 32 + row;
    float num[4];
#pragma unroll
    for (int i = 0; i < 4; ++i) num[i] = 0.f;
    for (int cc = 0; cc < nc; ++cc) {
        const float a = als[row][cc];
        const bf16x4_t ov = *reinterpret_cast<const bf16x4_t*>(
            (const bf16_t*)(base0 + (size_t)cc * PART_STRIDE_F + 512) +
            (size_t)ql * 64 + h0);
#pragma unroll
        for (int i = 0; i < 4; ++i) num[i] += a * (float)ov[i];
    }
    const float inv = dinv[row];
    float* op = out + ((size_t)b * S_LEN + qt * 256 + ql) * 64 + h0;
#pragma unroll
    for (int i = 0; i < 4; ++i) num[i] *= inv;
    *reinterpret_cast<float4*>(op) = *reinterpret_cast<float4*>(num);
}

// ---------------------------------------------------------------------------
// Kernel 2-fallback (used only if ws too small for partials).
// ---------------------------------------------------------------------------
__global__ __launch_bounds__(512)
void attn_fallback(
    const bf16_t* __restrict__ Qb, const bf16_t* __restrict__ Kb,
    const bf16_t* __restrict__ Vt, float* __restrict__ out)
{
    __shared__ bf16_t plds[8][16 * 64];
    __shared__ float  olds[8][16][64];
    __shared__ float  mlds[8][16];
    __shared__ float  llds[8][16];

    const int tid  = threadIdx.x;
    const int w    = tid >> 6;
    const int lane = tid & 63;
    const int g    = lane >> 4, n = lane & 15;
    const int id = blockIdx.x;
    const int b  = (id & 7) >> 1;
    const int p  = ((id & 1) << 6) + (id >> 3);
    const long bS  = (long)b * S_LEN;
    const long bV  = (long)b * 64;
    const int  swz = (n & 7) << 4;
    const f32x4_t zero = {0.f, 0.f, 0.f, 0.f};
    char* const pb = (char*)plds[w];

#pragma unroll 1
    for (int half = 0; half < 2; ++half) {
        const int tile = half ? (NQT - 1 - p) : p;
        const int q0   = tile * 16;
        const int nkb  = (q0 >> 6) + 1;

        const bf16_t* qbase = &Qb[(bS + q0 + n) * HDIM + g * 8];
        const bf16x8_t bq0 = *reinterpret_cast<const bf16x8_t*>(qbase);
        const bf16x8_t bq1 = *reinterpret_cast<const bf16x8_t*>(qbase + 32);

        f32x4_t o[4];
#pragma unroll
        for (int nt = 0; nt < 4; ++nt) o[nt] = zero;
        float m_run = -1e30f, l_par = 0.f;

#pragma unroll 1
        for (int j = w; j < nkb; j += 8) {
            const int k0 = j * 64;
            const bf16_t* kb = &Kb[(bS + k0 + n) * HDIM + g * 8];
            bf16x8_t kr[8];
#pragma unroll
            for (int f = 0; f < 4; ++f) {
                kr[2 * f]     = *reinterpret_cast<const bf16x8_t*>(kb + f * 16 * HDIM);
                kr[2 * f + 1] = *reinterpret_cast<const bf16x8_t*>(kb + f * 16 * HDIM + 32);
            }
            const bf16_t* vbp = &Vt[(bV + n) * S_LEN + k0 + g * 8];
            bf16x8_t vr[8];
#pragma unroll
            for (int ks = 0; ks < 2; ++ks)
#pragma unroll
                for (int nt = 0; nt < 4; ++nt)
                    vr[ks * 4 + nt] = *reinterpret_cast<const bf16x8_t*>(
                        vbp + (long)(nt * 16) * S_LEN + ks * 32);

            f32x4_t s[4];
#pragma unroll
            for (int f = 0; f < 4; ++f) {
                s[f] = __builtin_amdgcn_mfma_f32_16x16x32_bf16(kr[2 * f],     bq0, zero, 0, 0, 0);
                s[f] = __builtin_amdgcn_mfma_f32_16x16x32_bf16(kr[2 * f + 1], bq1, s[f], 0, 0, 0);
            }
            if (j == nkb - 1) {
                const int q = q0 + n;
#pragma unroll
                for (int f = 0; f < 4; ++f)
#pragma unroll
                    for (int r = 0; r < 4; ++r)
                        if (k0 + 16 * f + 4 * g + r > q) s[f][r] = -1e30f;
            }
            float pm = fmaxf(fmaxf(fmaxf(s[0][0], s[0][1]), fmaxf(s[0][2], s[0][3])),
                             fmaxf(fmaxf(s[1][0], s[1][1]), fmaxf(s[1][2], s[1][3])));
            pm = fmaxf(pm, fmaxf(fmaxf(fmaxf(s[2][0], s[2][1]), fmaxf(s[2][2], s[2][3])),
                                 fmaxf(fmaxf(s[3][0], s[3][1]), fmaxf(s[3][2], s[3][3]))));
            pm = fmaxf(pm, __shfl_xor(pm, 16));
            pm = fmaxf(pm, __shfl_xor(pm, 32));
            if (__any(pm > m_run + DTHR)) {
                const float mn = fmaxf(m_run, pm);
                const float al = ex2(m_run - mn);
                m_run = mn; l_par *= al;
#pragma unroll
                for (int r = 0; r < 4; ++r) {
                    const float ar = __shfl(al, 4 * g + r);
#pragma unroll
                    for (int nt = 0; nt < 4; ++nt) o[nt][r] *= ar;
                }
            }
#pragma unroll
            for (int f = 0; f < 4; ++f) {
                bf16x4_t pk;
#pragma unroll
                for (int r = 0; r < 4; ++r) {
                    const float p2 = ex2(s[f][r] - m_run);
                    l_par += p2;
                    pk[r] = (bf16_t)p2;
                }
                *reinterpret_cast<bf16x4_t*>(pb + n * 128 + ((32 * f + 8 * g) ^ swz)) = pk;
            }
#pragma unroll
            for (int ks = 0; ks < 2; ++ks) {
                const bf16x8_t pa = *reinterpret_cast<const bf16x8_t*>(
                    pb + n * 128 + ((64 * ks + 16 * g) ^ swz));
#pragma unroll
                for (int nt = 0; nt < 4; ++nt)
                    o[nt] = __builtin_amdgcn_mfma_f32_16x16x32_bf16(
                        pa, vr[ks * 4 + nt], o[nt], 0, 0, 0);
            }
        }

        float l_run = l_par;
        l_run += __shfl_xor(l_run, 16);
        l_run += __shfl_xor(l_run, 32);
        if (g == 0) { mlds[w][n] = m_run; llds[w][n] = l_run; }
#pragma unroll
        for (int nt = 0; nt < 4; ++nt)
#pragma unroll
            for (int r = 0; r < 4; ++r)
                olds[w][4 * g + r][nt * 16 + n] = o[nt][r];
        __syncthreads();
        {
            const int cc = tid & 63;
            const int rg = tid >> 6;
#pragma unroll
            for (int i = 0; i < 2; ++i) {
                const int row = rg * 2 + i;
                float mmx = mlds[0][row];
#pragma unroll
                for (int u = 1; u < 8; ++u) mmx = fmaxf(mmx, mlds[u][row]);
                float den = 0.f, num = 0.f;
#pragma unroll
                for (int u = 0; u < 8; ++u) {
                    const float a = ex2(mlds[u][row] - mmx);
                    den += llds[u][row] * a;
                    num += olds[u][row][cc] * a;
                }
                out[(bS + q0 + row) * HDIM + cc] = num / den;
            }
        }
        __syncthreads();
    }
}

// ---------------------------------------------------------------------------
extern "C" void kernel_launch(void* const* d_in, const int* in_sizes, int n_in,
                              void* d_out, int out_size, void* d_ws, size_t ws_size,
                              hipStream_t stream)
{
    const float* x  = (const float*)d_in[0];
    const float* Wk = (const float*)d_in[1];
    const float* bk = (const float*)d_in[2];
    const float* Wq = (const float*)d_in[3];
    const float* bq = (const float*)d_in[4];
    const float* Wv = (const float*)d_in[5];
    const float* bv = (const float*)d_in[6];
    float* out = (float*)d_out;

    const size_t elems = (size_t)BATCH * S_LEN * HDIM;  // 1,048,576
    bf16_t* Qb = (bf16_t*)d_ws;
    bf16_t* Kb = Qb + elems;
    bf16_t* Vt = Kb + elems;
    bf16_t* Wt = Vt + elems;                 // 192*1024 bf16
    float*  part = (float*)((char*)d_ws + 6684672);   // 256-aligned

    const size_t needed = 6684672ull + 544ull * (size_t)PART_STRIDE_F * 4ull;

    wt_kernel<<<dim3(DMODEL / 64, 3), 256, 0, stream>>>(Wk, Wq, Wv, Wt);
    qkv_mfma_kernel<<<256, 512, 0, stream>>>(x, Wt, bk, bq, bv, Qb, Kb, Vt);
    if (ws_size >= needed) {
        attn_fa<<<544, 512, 0, stream>>>(Qb, Kb, Vt, part);
        attn_merge<<<512, 512, 0, stream>>>(part, out);
    } else {
        attn_fallback<<<512, 512, 0, stream>>>(Qb, Kb, Vt, out);
    }
}